// Round 10
// baseline (516.546 us; speedup 1.0000x reference)
//
#include <hip/hip_runtime.h>
#include <hip/hip_bf16.h>

#define N_NODES 50000
#define N_EDGES 600000
#define N_GRAPHS 256
#define D 128
#define NTILES 1563  // ceil(50000/32)

typedef __bf16 bf16x8 __attribute__((ext_vector_type(8)));
typedef float f32x16 __attribute__((ext_vector_type(16)));
typedef unsigned short u16x8 __attribute__((ext_vector_type(8)));
typedef unsigned short u16x4 __attribute__((ext_vector_type(4)));

__device__ __forceinline__ float bf2f(unsigned short u) {
    unsigned v = ((unsigned)u) << 16;
    return __builtin_bit_cast(float, v);
}
__device__ __forceinline__ unsigned short f2bf(float f) {
    unsigned x = __builtin_bit_cast(unsigned, f);
    unsigned r = (x + 0x7fffu + ((x >> 16) & 1u)) >> 16;  // RNE
    return (unsigned short)r;
}

// ---------------- fused init: zero(deg+gsum+hist+cnt2) || pack_w || pre ----------------

#define ZERO_N (50048 + 32768 + 128)   // deg | gsum | hist(64) | cnt2(64)
#define ZERO_BLOCKS 324                // 324*256 = 82944 = ZERO_N
#define PACK_BLOCKS 256
#define PRE_BLOCKS 3125

__global__ __launch_bounds__(256) void init_kernel(
    int* __restrict__ deg_gsum,
    const float* __restrict__ Wl1, const float* __restrict__ Wr1,
    const float* __restrict__ Wl2, const float* __restrict__ Wr2,
    unsigned short* __restrict__ Wpk,
    const float* __restrict__ x, const float* __restrict__ Wpre,
    const float* __restrict__ bpre, unsigned short* __restrict__ h0) {
    int bb = blockIdx.x;
    if (bb < ZERO_BLOCKS) {
        int i = bb * 256 + threadIdx.x;
        if (i < ZERO_N) deg_gsum[i] = 0;
    } else if (bb < ZERO_BLOCKS + PACK_BLOCKS) {
        // fragment-major pack: B-frag (kt,ct): lane l elem j = W[kt*16+(l>>5)*8+j][(l&31)*4+ct]
        int tid = (bb - ZERO_BLOCKS) * 256 + threadIdx.x;  // < 65536
        int conv = tid >> 15;
        int e = tid & 32767;
        int j = e & 7, lane = (e >> 3) & 63, ct = (e >> 9) & 3, kt = e >> 11;
        int k = kt * 16 + (lane >> 5) * 8 + j;
        int col = (lane & 31) * 4 + ct;
        const float* Wl = conv ? Wl2 : Wl1;
        const float* Wr = conv ? Wr2 : Wr1;
        float v = (k < 128) ? Wl[k * 128 + col] : Wr[(k - 128) * 128 + col];
        Wpk[tid] = f2bf(v);
    } else {
        int idx = (bb - ZERO_BLOCKS - PACK_BLOCKS) * 256 + threadIdx.x;  // node*16+slot
        if (idx >= N_NODES * 16) return;
        int node = idx >> 4, j8 = (idx & 15) * 8;
        const float* xr = x + node * 5;
        float acc[8];
#pragma unroll
        for (int c = 0; c < 8; ++c) acc[c] = bpre[j8 + c];
#pragma unroll
        for (int k = 0; k < 5; ++k) {
            float xv = xr[k];
#pragma unroll
            for (int c = 0; c < 8; ++c) acc[c] += xv * Wpre[k * D + j8 + c];
        }
        u16x8 o;
#pragma unroll
        for (int c = 0; c < 8; ++c) o[c] = f2bf(fmaxf(acc[c], 0.f));
        *(u16x8*)&h0[(size_t)node * D + j8] = o;
    }
}

// ---------------- CSR build ----------------

__global__ void deg_kernel(const int* __restrict__ dst, int* __restrict__ deg) {
    int e = blockIdx.x * 256 + threadIdx.x;
    if (e < N_EDGES) atomicAdd(&deg[dst[e]], 1);
}

__global__ __launch_bounds__(1024) void scan_blk_kernel(const int* __restrict__ deg,
                                                        int* __restrict__ partial,
                                                        int* __restrict__ bsum) {
    __shared__ int tmp[1024];
    int tid = threadIdx.x;
    int i = blockIdx.x * 1024 + tid;
    int v = (i < N_NODES) ? deg[i] : 0;
    tmp[tid] = v;
    __syncthreads();
    for (int off = 1; off < 1024; off <<= 1) {
        int add = (tid >= off) ? tmp[tid - off] : 0;
        __syncthreads();
        tmp[tid] += add;
        __syncthreads();
    }
    if (i < N_NODES) partial[i] = tmp[tid] - v;
    if (tid == 1023) bsum[blockIdx.x] = tmp[tid];
}

__global__ __launch_bounds__(256) void scan_fix_kernel(const int* __restrict__ partial,
                                                       const int* __restrict__ bsum,
                                                       const int* __restrict__ deg,
                                                       int* __restrict__ row_start,
                                                       int* __restrict__ cursor,
                                                       float* __restrict__ deg_inv,
                                                       int* __restrict__ hist) {
    __shared__ int boff_s;
    int bucket = (blockIdx.x * 256) >> 10;
    if (threadIdx.x < 64) {
        int l = threadIdx.x;
        int v = (l < bucket) ? bsum[l] : 0;
#pragma unroll
        for (int m = 32; m >= 1; m >>= 1) v += __shfl_xor(v, m);
        if (l == 0) boff_s = v;
    }
    __syncthreads();
    int i = blockIdx.x * 256 + threadIdx.x;
    if (i >= N_NODES) return;
    int dg = deg[i];
    int rs = partial[i] + boff_s;
    row_start[i] = rs;
    cursor[i] = rs;
    deg_inv[i] = 1.0f / fmaxf((float)dg, 1.0f);
    atomicAdd(&hist[dg < 63 ? dg : 63], 1);  // degree histogram for perm sort
    if (i == N_NODES - 1) row_start[N_NODES] = rs + dg;
}

// counting-sort scatter: perm = node ids ordered by (clamped) degree
__global__ __launch_bounds__(256) void perm_kernel(const int* __restrict__ deg,
                                                   const int* __restrict__ hist,
                                                   int* __restrict__ cnt2,
                                                   int* __restrict__ perm) {
    __shared__ int boff[64];
    int t = threadIdx.x;
    if (t < 64) {
        int v = hist[t];
        int incl = v;
#pragma unroll
        for (int m = 1; m < 64; m <<= 1) {
            int u = __shfl_up(incl, m);
            if (t >= m) incl += u;
        }
        boff[t] = incl - v;  // exclusive bin offset
    }
    __syncthreads();
    int i = blockIdx.x * 256 + t;
    if (i >= N_NODES) return;
    int dg = deg[i];
    int bin = dg < 63 ? dg : 63;
    int pos = boff[bin] + atomicAdd(&cnt2[bin], 1);
    perm[pos] = i;
}

__global__ void fill_kernel(const int* __restrict__ src, const int* __restrict__ dst,
                            int* __restrict__ cursor, int* __restrict__ csr_src) {
    int e = blockIdx.x * 256 + threadIdx.x;
    if (e < N_EDGES) {
        int slot = atomicAdd(&cursor[dst[e]], 1);
        csr_src[slot] = src[e];
    }
}

// ---------------- mean aggregate: degree-sorted, one node per 16-lane group ----------------

__global__ __launch_bounds__(256) void agg_kernel(const unsigned short* __restrict__ h,
                                                  const int* __restrict__ row_start,
                                                  const int* __restrict__ csr_src,
                                                  const float* __restrict__ deg_inv,
                                                  const int* __restrict__ perm,
                                                  unsigned short* __restrict__ aggb) {
    int idx = blockIdx.x * 16 + (threadIdx.x >> 4);
    int fl = threadIdx.x & 15;  // feature slot: features fl*8 .. fl*8+7
    if (idx >= N_NODES) return;
    int node = perm[idx];  // degree-sorted -> uniform trip counts within wave
    int s = row_start[node], e = row_start[node + 1];
    float a[8] = {0.f, 0.f, 0.f, 0.f, 0.f, 0.f, 0.f, 0.f};
    int i = s;
    for (; i + 7 < e; i += 8) {
        int c[8];
#pragma unroll
        for (int q = 0; q < 8; ++q) c[q] = csr_src[i + q];
        bf16x8 v[8];
#pragma unroll
        for (int q = 0; q < 8; ++q) v[q] = *(const bf16x8*)(h + (size_t)c[q] * D + fl * 8);
#pragma unroll
        for (int q = 0; q < 8; ++q)
#pragma unroll
            for (int j = 0; j < 8; ++j) a[j] += (float)v[q][j];
    }
    for (; i + 3 < e; i += 4) {
        int c[4];
#pragma unroll
        for (int q = 0; q < 4; ++q) c[q] = csr_src[i + q];
        bf16x8 v[4];
#pragma unroll
        for (int q = 0; q < 4; ++q) v[q] = *(const bf16x8*)(h + (size_t)c[q] * D + fl * 8);
#pragma unroll
        for (int q = 0; q < 4; ++q)
#pragma unroll
            for (int j = 0; j < 8; ++j) a[j] += (float)v[q][j];
    }
    for (; i < e; ++i) {
        int c0 = csr_src[i];
        bf16x8 v0 = *(const bf16x8*)(h + (size_t)c0 * D + fl * 8);
#pragma unroll
        for (int j = 0; j < 8; ++j) a[j] += (float)v0[j];
    }
    float di = deg_inv[node];
    u16x8 o;
#pragma unroll
    for (int j = 0; j < 8; ++j) o[j] = f2bf(a[j] * di);
    *(u16x8*)(aggb + (size_t)node * D + fl * 8) = o;
}

// ---------------- SAGE linear via MFMA with LDS-staged weights ----------------

__global__ __launch_bounds__(256) void lin_mfma_kernel(const unsigned short* __restrict__ hin,
                                                       const unsigned short* __restrict__ aggb,
                                                       const unsigned short* __restrict__ Wp,
                                                       const float* __restrict__ b,
                                                       unsigned short* __restrict__ hout) {
    __shared__ unsigned short Wls[32768];  // 64 KB

    int t = threadIdx.x;
    int wg = blockIdx.x * 4 + (t >> 6);
    int lane = t & 63;
    int l31 = lane & 31, hi = lane >> 5;
    int row0 = wg * 32;
    int rowg = row0 + l31;
    bool wvalid = wg < NTILES;
    int rowc = (wvalid && rowg < N_NODES) ? rowg : (N_NODES - 1);

    // prefetch A-fragments (16 x 16B per lane) while W streams to LDS
    const unsigned short* arow = aggb + (size_t)rowc * D + hi * 8;
    const unsigned short* hrow = hin + (size_t)rowc * D + hi * 8;
    bf16x8 afr[16];
#pragma unroll
    for (int kt = 0; kt < 8; ++kt) afr[kt] = *(const bf16x8*)(arow + kt * 16);
#pragma unroll
    for (int kt = 0; kt < 8; ++kt) afr[8 + kt] = *(const bf16x8*)(hrow + kt * 16);

    // stage the 64KB weight table: 4096 x 16B, 256 threads x 16 iters
#pragma unroll
    for (int q = 0; q < 16; ++q) {
        int idx = q * 256 + t;
        *(u16x8*)&Wls[idx * 8] = *(const u16x8*)&Wp[idx * 8];
    }
    __syncthreads();

    if (!wvalid) return;

    const unsigned short* wbase = Wls + lane * 8;

    f32x16 acc[4];
#pragma unroll
    for (int ct = 0; ct < 4; ++ct) acc[ct] = (f32x16)(0.0f);

#pragma unroll
    for (int kt = 0; kt < 16; ++kt) {
#pragma unroll
        for (int ct = 0; ct < 4; ++ct) {
            bf16x8 bfrag = *(const bf16x8*)(wbase + (kt * 4 + ct) * 512);
            acc[ct] = __builtin_amdgcn_mfma_f32_32x32x16_bf16(afr[kt], bfrag, acc[ct], 0, 0, 0);
        }
    }

    // epilogue: +bias, per-row L2 norm, relu, 8B store (4 consecutive cols/lane)
    float4 b4 = *(const float4*)&b[l31 * 4];
    float bb[4] = {b4.x, b4.y, b4.z, b4.w};

#pragma unroll
    for (int r = 0; r < 16; ++r) {
        float v[4];
        float ss = 0.f;
#pragma unroll
        for (int ct = 0; ct < 4; ++ct) {
            v[ct] = acc[ct][r] + bb[ct];
            ss += v[ct] * v[ct];
        }
        ss += __shfl_xor(ss, 1);
        ss += __shfl_xor(ss, 2);
        ss += __shfl_xor(ss, 4);
        ss += __shfl_xor(ss, 8);
        ss += __shfl_xor(ss, 16);
        float sc = 1.0f / fmaxf(sqrtf(ss), 1e-12f);
        int row = row0 + (r & 3) + 8 * (r >> 2) + 4 * hi;
        if (row < N_NODES) {
            u16x4 o;
#pragma unroll
            for (int ct = 0; ct < 4; ++ct) o[ct] = f2bf(fmaxf(v[ct] * sc, 0.f));
            *(u16x4*)(hout + (size_t)row * D + l31 * 4) = o;
        }
    }
}

// ---------------- global mean pool: chunk-parallel run-length atomics ----------------

__global__ __launch_bounds__(128) void pool_sum_kernel(const unsigned short* __restrict__ h,
                                                       const int* __restrict__ batch,
                                                       float* __restrict__ gsum) {
    int j = threadIdx.x;
    int i0 = blockIdx.x * 128;
    int i1 = i0 + 128;
    if (i1 > N_NODES) i1 = N_NODES;
    __shared__ int bids[128];
    if (i0 + j < N_NODES) bids[j] = batch[i0 + j];
    __syncthreads();
    float acc = 0.f;
    int cur = bids[0];
    for (int i = i0; i < i1; ++i) {
        int bid = bids[i - i0];
        if (bid != cur) {
            atomicAdd(&gsum[cur * D + j], acc);
            acc = 0.f;
            cur = bid;
        }
        acc += bf2f(h[(size_t)i * D + j]);
    }
    atomicAdd(&gsum[cur * D + j], acc);
}

// ---------------- head MLP (f32), fused mean-divide via binary search ----------------

__global__ __launch_bounds__(128) void mlp_kernel(const float* __restrict__ gsum,
                                                  const int* __restrict__ batch,
                                                  const float* __restrict__ Wp1,
                                                  const float* __restrict__ bp1,
                                                  const float* __restrict__ Wp2,
                                                  const float* __restrict__ bp2,
                                                  const float* __restrict__ Wout,
                                                  const float* __restrict__ bout,
                                                  float* __restrict__ out) {
    __shared__ float gin[128], y1[128], y2[64];
    __shared__ float cnt_s;
    int gid = blockIdx.x, j = threadIdx.x;
    if (j == 0) {
        int lo = 0, hi = N_NODES;
        while (lo < hi) { int m = (lo + hi) >> 1; if (batch[m] < gid) lo = m + 1; else hi = m; }
        int start = lo;
        lo = start; hi = N_NODES;
        while (lo < hi) { int m = (lo + hi) >> 1; if (batch[m] < gid + 1) lo = m + 1; else hi = m; }
        cnt_s = fmaxf((float)(lo - start), 1.0f);
    }
    __syncthreads();
    gin[j] = gsum[gid * 128 + j] / cnt_s;
    __syncthreads();
    float a = bp1[j];
    for (int k = 0; k < 128; ++k) a += gin[k] * Wp1[k * 128 + j];
    y1[j] = fmaxf(a, 0.f);
    __syncthreads();
    if (j < 64) {
        float a2 = bp2[j];
        for (int k = 0; k < 128; ++k) a2 += y1[k] * Wp2[k * 64 + j];
        y2[j] = fmaxf(a2, 0.f);
    }
    __syncthreads();
    if (j < 64) {
        float v = y2[j] * Wout[j];
#pragma unroll
        for (int m = 32; m >= 1; m >>= 1) v += __shfl_xor(v, m);
        if (j == 0) out[gid] = v + bout[0];
    }
}

// ---------------- launch ----------------

extern "C" void kernel_launch(void* const* d_in, const int* in_sizes, int n_in,
                              void* d_out, int out_size, void* d_ws, size_t ws_size,
                              hipStream_t stream) {
    const float* x     = (const float*)d_in[0];
    const int*   ei    = (const int*)d_in[1];
    const int*   batch = (const int*)d_in[2];
    const float* W_pre = (const float*)d_in[3];
    const float* b_pre = (const float*)d_in[4];
    const float* W1_l  = (const float*)d_in[5];
    const float* b1    = (const float*)d_in[6];
    const float* W1_r  = (const float*)d_in[7];
    const float* W2_l  = (const float*)d_in[8];
    const float* b2    = (const float*)d_in[9];
    const float* W2_r  = (const float*)d_in[10];
    const float* W_p1  = (const float*)d_in[11];
    const float* b_p1  = (const float*)d_in[12];
    const float* W_p2  = (const float*)d_in[13];
    const float* b_p2  = (const float*)d_in[14];
    const float* W_out = (const float*)d_in[15];
    const float* b_out = (const float*)d_in[16];

    const int* src = ei;
    const int* dst = ei + N_EDGES;

    size_t off = 0;
    auto carve = [&](size_t bytes) {
        void* p = (char*)d_ws + off;
        off += (bytes + 255) & ~(size_t)255;
        return p;
    };
    // deg | gsum | hist | cnt2 zeroed together in init
    int* deg       = (int*)carve(50048 * 4 + 32768 * 4 + 128 * 4);
    float* gsum    = (float*)(deg + 50048);
    int* hist      = (int*)(deg + 50048 + 32768);
    int* cnt2      = hist + 64;
    int* row_start = (int*)carve((N_NODES + 1) * 4);
    int* cursor    = (int*)carve(N_NODES * 4);
    int* csr_src   = (int*)carve(N_EDGES * 4);
    float* deg_inv = (float*)carve(N_NODES * 4);
    int* partial   = (int*)carve(N_NODES * 4);
    int* bsum      = (int*)carve(64 * 4);
    int* perm      = (int*)carve(N_NODES * 4);
    unsigned short* h0   = (unsigned short*)carve((size_t)N_NODES * D * 2);
    unsigned short* h1   = (unsigned short*)carve((size_t)N_NODES * D * 2);
    unsigned short* aggb = (unsigned short*)carve((size_t)N_NODES * D * 2);
    unsigned short* Wp   = (unsigned short*)carve(65536 * 2);
    unsigned short* h2 = h0;  // reuse: h0 dead after conv1's lin
    float* out = (float*)d_out;

    const int nblk_scan = (N_NODES + 1023) / 1024;  // 49

    init_kernel<<<ZERO_BLOCKS + PACK_BLOCKS + PRE_BLOCKS, 256, 0, stream>>>(
        deg, W1_l, W1_r, W2_l, W2_r, Wp, x, W_pre, b_pre, h0);

    deg_kernel<<<(N_EDGES + 255) / 256, 256, 0, stream>>>(dst, deg);
    scan_blk_kernel<<<nblk_scan, 1024, 0, stream>>>(deg, partial, bsum);
    scan_fix_kernel<<<(N_NODES + 255) / 256, 256, 0, stream>>>(partial, bsum, deg,
                                                               row_start, cursor, deg_inv,
                                                               hist);
    perm_kernel<<<(N_NODES + 255) / 256, 256, 0, stream>>>(deg, hist, cnt2, perm);
    fill_kernel<<<(N_EDGES + 255) / 256, 256, 0, stream>>>(src, dst, cursor, csr_src);

    // conv1
    agg_kernel<<<(N_NODES + 15) / 16, 256, 0, stream>>>(h0, row_start, csr_src, deg_inv,
                                                        perm, aggb);
    lin_mfma_kernel<<<(NTILES + 3) / 4, 256, 0, stream>>>(h0, aggb, Wp, b1, h1);

    // conv2
    agg_kernel<<<(N_NODES + 15) / 16, 256, 0, stream>>>(h1, row_start, csr_src, deg_inv,
                                                        perm, aggb);
    lin_mfma_kernel<<<(NTILES + 3) / 4, 256, 0, stream>>>(h1, aggb, Wp + 32768, b2, h2);

    // pool + head
    pool_sum_kernel<<<(N_NODES + 127) / 128, 128, 0, stream>>>(h2, batch, gsum);
    mlp_kernel<<<N_GRAPHS, 128, 0, stream>>>(gsum, batch, W_p1, b_p1, W_p2, b_p2,
                                             W_out, b_out, out);
}

// Round 11
// 208.757 us; speedup vs baseline: 2.4744x; 2.4744x over previous
//
#include <hip/hip_runtime.h>
#include <hip/hip_bf16.h>

#define N_NODES 50000
#define N_EDGES 600000
#define N_GRAPHS 256
#define D 128
#define NTILES 1563  // ceil(50000/32)

typedef __bf16 bf16x8 __attribute__((ext_vector_type(8)));
typedef float f32x16 __attribute__((ext_vector_type(16)));
typedef unsigned short u16x8 __attribute__((ext_vector_type(8)));
typedef unsigned short u16x4 __attribute__((ext_vector_type(4)));

__device__ __forceinline__ float bf2f(unsigned short u) {
    unsigned v = ((unsigned)u) << 16;
    return __builtin_bit_cast(float, v);
}
__device__ __forceinline__ unsigned short f2bf(float f) {
    unsigned x = __builtin_bit_cast(unsigned, f);
    unsigned r = (x + 0x7fffu + ((x >> 16) & 1u)) >> 16;  // RNE
    return (unsigned short)r;
}

// ---------------- fused init: zero(deg+gsum+hist+cnt2) || pack_w || pre ----------------

#define ZERO_N (50048 + 32768 + 128)   // deg | gsum | hist(64) | cnt2(64)
#define ZERO_BLOCKS 324
#define PACK_BLOCKS 256
#define PRE_BLOCKS 3125

__global__ __launch_bounds__(256) void init_kernel(
    int* __restrict__ deg_gsum,
    const float* __restrict__ Wl1, const float* __restrict__ Wr1,
    const float* __restrict__ Wl2, const float* __restrict__ Wr2,
    unsigned short* __restrict__ Wpk,
    const float* __restrict__ x, const float* __restrict__ Wpre,
    const float* __restrict__ bpre, unsigned short* __restrict__ h0) {
    int bb = blockIdx.x;
    if (bb < ZERO_BLOCKS) {
        int i = bb * 256 + threadIdx.x;
        if (i < ZERO_N) deg_gsum[i] = 0;
    } else if (bb < ZERO_BLOCKS + PACK_BLOCKS) {
        // fragment-major pack: B-frag (kt,ct): lane l elem j = W[kt*16+(l>>5)*8+j][(l&31)*4+ct]
        int tid = (bb - ZERO_BLOCKS) * 256 + threadIdx.x;  // < 65536
        int conv = tid >> 15;
        int e = tid & 32767;
        int j = e & 7, lane = (e >> 3) & 63, ct = (e >> 9) & 3, kt = e >> 11;
        int k = kt * 16 + (lane >> 5) * 8 + j;
        int col = (lane & 31) * 4 + ct;
        const float* Wl = conv ? Wl2 : Wl1;
        const float* Wr = conv ? Wr2 : Wr1;
        float v = (k < 128) ? Wl[k * 128 + col] : Wr[(k - 128) * 128 + col];
        Wpk[tid] = f2bf(v);
    } else {
        int idx = (bb - ZERO_BLOCKS - PACK_BLOCKS) * 256 + threadIdx.x;  // node*16+slot
        if (idx >= N_NODES * 16) return;
        int node = idx >> 4, j8 = (idx & 15) * 8;
        const float* xr = x + node * 5;
        float acc[8];
#pragma unroll
        for (int c = 0; c < 8; ++c) acc[c] = bpre[j8 + c];
#pragma unroll
        for (int k = 0; k < 5; ++k) {
            float xv = xr[k];
#pragma unroll
            for (int c = 0; c < 8; ++c) acc[c] += xv * Wpre[k * D + j8 + c];
        }
        u16x8 o;
#pragma unroll
        for (int c = 0; c < 8; ++c) o[c] = f2bf(fmaxf(acc[c], 0.f));
        *(u16x8*)&h0[(size_t)node * D + j8] = o;
    }
}

// ---------------- CSR build ----------------

__global__ void deg_kernel(const int* __restrict__ dst, int* __restrict__ deg) {
    int e = blockIdx.x * 256 + threadIdx.x;
    if (e < N_EDGES) atomicAdd(&deg[dst[e]], 1);
}

__global__ __launch_bounds__(1024) void scan_blk_kernel(const int* __restrict__ deg,
                                                        int* __restrict__ partial,
                                                        int* __restrict__ bsum) {
    __shared__ int tmp[1024];
    int tid = threadIdx.x;
    int i = blockIdx.x * 1024 + tid;
    int v = (i < N_NODES) ? deg[i] : 0;
    tmp[tid] = v;
    __syncthreads();
    for (int off = 1; off < 1024; off <<= 1) {
        int add = (tid >= off) ? tmp[tid - off] : 0;
        __syncthreads();
        tmp[tid] += add;
        __syncthreads();
    }
    if (i < N_NODES) partial[i] = tmp[tid] - v;
    if (tid == 1023) bsum[blockIdx.x] = tmp[tid];
}

// scan_fix + LDS-reduced degree histogram (no hot global atomics)
__global__ __launch_bounds__(256) void scan_fix_kernel(const int* __restrict__ partial,
                                                       const int* __restrict__ bsum,
                                                       const int* __restrict__ deg,
                                                       int* __restrict__ row_start,
                                                       int* __restrict__ cursor,
                                                       float* __restrict__ deg_inv,
                                                       int* __restrict__ hist) {
    __shared__ int boff_s;
    __shared__ int lhist[64];
    int t = threadIdx.x;
    if (t < 64) lhist[t] = 0;
    int bucket = (blockIdx.x * 256) >> 10;
    if (t < 64) {
        int v = (t < bucket) ? bsum[t] : 0;
#pragma unroll
        for (int m = 32; m >= 1; m >>= 1) v += __shfl_xor(v, m);
        if (t == 0) boff_s = v;
    }
    __syncthreads();
    int i = blockIdx.x * 256 + t;
    if (i < N_NODES) {
        int dg = deg[i];
        int rs = partial[i] + boff_s;
        row_start[i] = rs;
        cursor[i] = rs;
        deg_inv[i] = 1.0f / fmaxf((float)dg, 1.0f);
        atomicAdd(&lhist[dg < 63 ? dg : 63], 1);
        if (i == N_NODES - 1) row_start[N_NODES] = rs + dg;
    }
    __syncthreads();
    if (t < 64 && lhist[t]) atomicAdd(&hist[t], lhist[t]);
}

// counting-sort scatter with per-block reservation (1 global atomic per bin per block)
__global__ __launch_bounds__(256) void perm_kernel(const int* __restrict__ deg,
                                                   const int* __restrict__ hist,
                                                   int* __restrict__ cnt2,
                                                   int* __restrict__ perm) {
    __shared__ int boff[64];
    __shared__ int lcnt[64];
    __shared__ int base[64];
    int t = threadIdx.x;
    if (t < 64) {
        lcnt[t] = 0;
        int v = hist[t];
        int incl = v;
#pragma unroll
        for (int m = 1; m < 64; m <<= 1) {
            int u = __shfl_up(incl, m);
            if (t >= m) incl += u;
        }
        boff[t] = incl - v;  // exclusive bin offset
    }
    __syncthreads();
    int i = blockIdx.x * 256 + t;
    bool valid = i < N_NODES;
    int bin = 0, myrank = 0;
    if (valid) {
        int dg = deg[i];
        bin = dg < 63 ? dg : 63;
        myrank = atomicAdd(&lcnt[bin], 1);
    }
    __syncthreads();
    if (t < 64 && lcnt[t]) base[t] = atomicAdd(&cnt2[t], lcnt[t]);
    __syncthreads();
    if (valid) perm[boff[bin] + base[bin] + myrank] = i;
}

__global__ void fill_kernel(const int* __restrict__ src, const int* __restrict__ dst,
                            int* __restrict__ cursor, int* __restrict__ csr_src) {
    int e = blockIdx.x * 256 + threadIdx.x;
    if (e < N_EDGES) {
        int slot = atomicAdd(&cursor[dst[e]], 1);
        csr_src[slot] = src[e];
    }
}

// ---------------- mean aggregate: degree-sorted, one node per 16-lane group ----------------

__global__ __launch_bounds__(256) void agg_kernel(const unsigned short* __restrict__ h,
                                                  const int* __restrict__ row_start,
                                                  const int* __restrict__ csr_src,
                                                  const float* __restrict__ deg_inv,
                                                  const int* __restrict__ perm,
                                                  unsigned short* __restrict__ aggb) {
    int idx = blockIdx.x * 16 + (threadIdx.x >> 4);
    int fl = threadIdx.x & 15;  // feature slot: features fl*8 .. fl*8+7
    if (idx >= N_NODES) return;
    int node = perm[idx];  // degree-sorted -> uniform trip counts within wave
    int s = row_start[node], e = row_start[node + 1];
    float a[8] = {0.f, 0.f, 0.f, 0.f, 0.f, 0.f, 0.f, 0.f};
    int i = s;
    for (; i + 7 < e; i += 8) {
        int c[8];
#pragma unroll
        for (int q = 0; q < 8; ++q) c[q] = csr_src[i + q];
        bf16x8 v[8];
#pragma unroll
        for (int q = 0; q < 8; ++q) v[q] = *(const bf16x8*)(h + (size_t)c[q] * D + fl * 8);
#pragma unroll
        for (int q = 0; q < 8; ++q)
#pragma unroll
            for (int j = 0; j < 8; ++j) a[j] += (float)v[q][j];
    }
    for (; i + 3 < e; i += 4) {
        int c[4];
#pragma unroll
        for (int q = 0; q < 4; ++q) c[q] = csr_src[i + q];
        bf16x8 v[4];
#pragma unroll
        for (int q = 0; q < 4; ++q) v[q] = *(const bf16x8*)(h + (size_t)c[q] * D + fl * 8);
#pragma unroll
        for (int q = 0; q < 4; ++q)
#pragma unroll
            for (int j = 0; j < 8; ++j) a[j] += (float)v[q][j];
    }
    for (; i < e; ++i) {
        int c0 = csr_src[i];
        bf16x8 v0 = *(const bf16x8*)(h + (size_t)c0 * D + fl * 8);
#pragma unroll
        for (int j = 0; j < 8; ++j) a[j] += (float)v0[j];
    }
    float di = deg_inv[node];
    u16x8 o;
#pragma unroll
    for (int j = 0; j < 8; ++j) o[j] = f2bf(a[j] * di);
    *(u16x8*)(aggb + (size_t)node * D + fl * 8) = o;
}

// ---------------- SAGE linear via MFMA with LDS-staged weights ----------------

__global__ __launch_bounds__(256) void lin_mfma_kernel(const unsigned short* __restrict__ hin,
                                                       const unsigned short* __restrict__ aggb,
                                                       const unsigned short* __restrict__ Wp,
                                                       const float* __restrict__ b,
                                                       unsigned short* __restrict__ hout) {
    __shared__ unsigned short Wls[32768];  // 64 KB

    int t = threadIdx.x;
    int wg = blockIdx.x * 4 + (t >> 6);
    int lane = t & 63;
    int l31 = lane & 31, hi = lane >> 5;
    int row0 = wg * 32;
    int rowg = row0 + l31;
    bool wvalid = wg < NTILES;
    int rowc = (wvalid && rowg < N_NODES) ? rowg : (N_NODES - 1);

    // prefetch A-fragments (16 x 16B per lane) while W streams to LDS
    const unsigned short* arow = aggb + (size_t)rowc * D + hi * 8;
    const unsigned short* hrow = hin + (size_t)rowc * D + hi * 8;
    bf16x8 afr[16];
#pragma unroll
    for (int kt = 0; kt < 8; ++kt) afr[kt] = *(const bf16x8*)(arow + kt * 16);
#pragma unroll
    for (int kt = 0; kt < 8; ++kt) afr[8 + kt] = *(const bf16x8*)(hrow + kt * 16);

    // stage the 64KB weight table: 4096 x 16B, 256 threads x 16 iters
#pragma unroll
    for (int q = 0; q < 16; ++q) {
        int idx = q * 256 + t;
        *(u16x8*)&Wls[idx * 8] = *(const u16x8*)&Wp[idx * 8];
    }
    __syncthreads();

    if (!wvalid) return;

    const unsigned short* wbase = Wls + lane * 8;

    f32x16 acc[4];
#pragma unroll
    for (int ct = 0; ct < 4; ++ct) acc[ct] = (f32x16)(0.0f);

#pragma unroll
    for (int kt = 0; kt < 16; ++kt) {
#pragma unroll
        for (int ct = 0; ct < 4; ++ct) {
            bf16x8 bfrag = *(const bf16x8*)(wbase + (kt * 4 + ct) * 512);
            acc[ct] = __builtin_amdgcn_mfma_f32_32x32x16_bf16(afr[kt], bfrag, acc[ct], 0, 0, 0);
        }
    }

    // epilogue: +bias, per-row L2 norm, relu, 8B store (4 consecutive cols/lane)
    float4 b4 = *(const float4*)&b[l31 * 4];
    float bb[4] = {b4.x, b4.y, b4.z, b4.w};

#pragma unroll
    for (int r = 0; r < 16; ++r) {
        float v[4];
        float ss = 0.f;
#pragma unroll
        for (int ct = 0; ct < 4; ++ct) {
            v[ct] = acc[ct][r] + bb[ct];
            ss += v[ct] * v[ct];
        }
        ss += __shfl_xor(ss, 1);
        ss += __shfl_xor(ss, 2);
        ss += __shfl_xor(ss, 4);
        ss += __shfl_xor(ss, 8);
        ss += __shfl_xor(ss, 16);
        float sc = 1.0f / fmaxf(sqrtf(ss), 1e-12f);
        int row = row0 + (r & 3) + 8 * (r >> 2) + 4 * hi;
        if (row < N_NODES) {
            u16x4 o;
#pragma unroll
            for (int ct = 0; ct < 4; ++ct) o[ct] = f2bf(fmaxf(v[ct] * sc, 0.f));
            *(u16x4*)(hout + (size_t)row * D + l31 * 4) = o;
        }
    }
}

// ---------------- global mean pool: chunk-parallel run-length atomics ----------------

__global__ __launch_bounds__(128) void pool_sum_kernel(const unsigned short* __restrict__ h,
                                                       const int* __restrict__ batch,
                                                       float* __restrict__ gsum) {
    int j = threadIdx.x;
    int i0 = blockIdx.x * 128;
    int i1 = i0 + 128;
    if (i1 > N_NODES) i1 = N_NODES;
    __shared__ int bids[128];
    if (i0 + j < N_NODES) bids[j] = batch[i0 + j];
    __syncthreads();
    float acc = 0.f;
    int cur = bids[0];
    for (int i = i0; i < i1; ++i) {
        int bid = bids[i - i0];
        if (bid != cur) {
            atomicAdd(&gsum[cur * D + j], acc);
            acc = 0.f;
            cur = bid;
        }
        acc += bf2f(h[(size_t)i * D + j]);
    }
    atomicAdd(&gsum[cur * D + j], acc);
}

// ---------------- head MLP (f32), fused mean-divide via binary search ----------------

__global__ __launch_bounds__(128) void mlp_kernel(const float* __restrict__ gsum,
                                                  const int* __restrict__ batch,
                                                  const float* __restrict__ Wp1,
                                                  const float* __restrict__ bp1,
                                                  const float* __restrict__ Wp2,
                                                  const float* __restrict__ bp2,
                                                  const float* __restrict__ Wout,
                                                  const float* __restrict__ bout,
                                                  float* __restrict__ out) {
    __shared__ float gin[128], y1[128], y2[64];
    __shared__ float cnt_s;
    int gid = blockIdx.x, j = threadIdx.x;
    if (j == 0) {
        int lo = 0, hi = N_NODES;
        while (lo < hi) { int m = (lo + hi) >> 1; if (batch[m] < gid) lo = m + 1; else hi = m; }
        int start = lo;
        lo = start; hi = N_NODES;
        while (lo < hi) { int m = (lo + hi) >> 1; if (batch[m] < gid + 1) lo = m + 1; else hi = m; }
        cnt_s = fmaxf((float)(lo - start), 1.0f);
    }
    __syncthreads();
    gin[j] = gsum[gid * 128 + j] / cnt_s;
    __syncthreads();
    float a = bp1[j];
    for (int k = 0; k < 128; ++k) a += gin[k] * Wp1[k * 128 + j];
    y1[j] = fmaxf(a, 0.f);
    __syncthreads();
    if (j < 64) {
        float a2 = bp2[j];
        for (int k = 0; k < 128; ++k) a2 += y1[k] * Wp2[k * 64 + j];
        y2[j] = fmaxf(a2, 0.f);
    }
    __syncthreads();
    if (j < 64) {
        float v = y2[j] * Wout[j];
#pragma unroll
        for (int m = 32; m >= 1; m >>= 1) v += __shfl_xor(v, m);
        if (j == 0) out[gid] = v + bout[0];
    }
}

// ---------------- launch ----------------

extern "C" void kernel_launch(void* const* d_in, const int* in_sizes, int n_in,
                              void* d_out, int out_size, void* d_ws, size_t ws_size,
                              hipStream_t stream) {
    const float* x     = (const float*)d_in[0];
    const int*   ei    = (const int*)d_in[1];
    const int*   batch = (const int*)d_in[2];
    const float* W_pre = (const float*)d_in[3];
    const float* b_pre = (const float*)d_in[4];
    const float* W1_l  = (const float*)d_in[5];
    const float* b1    = (const float*)d_in[6];
    const float* W1_r  = (const float*)d_in[7];
    const float* W2_l  = (const float*)d_in[8];
    const float* b2    = (const float*)d_in[9];
    const float* W2_r  = (const float*)d_in[10];
    const float* W_p1  = (const float*)d_in[11];
    const float* b_p1  = (const float*)d_in[12];
    const float* W_p2  = (const float*)d_in[13];
    const float* b_p2  = (const float*)d_in[14];
    const float* W_out = (const float*)d_in[15];
    const float* b_out = (const float*)d_in[16];

    const int* src = ei;
    const int* dst = ei + N_EDGES;

    size_t off = 0;
    auto carve = [&](size_t bytes) {
        void* p = (char*)d_ws + off;
        off += (bytes + 255) & ~(size_t)255;
        return p;
    };
    // deg | gsum | hist | cnt2 zeroed together in init
    int* deg       = (int*)carve(50048 * 4 + 32768 * 4 + 128 * 4);
    float* gsum    = (float*)(deg + 50048);
    int* hist      = (int*)(deg + 50048 + 32768);
    int* cnt2      = hist + 64;
    int* row_start = (int*)carve((N_NODES + 1) * 4);
    int* cursor    = (int*)carve(N_NODES * 4);
    int* csr_src   = (int*)carve(N_EDGES * 4);
    float* deg_inv = (float*)carve(N_NODES * 4);
    int* partial   = (int*)carve(N_NODES * 4);
    int* bsum      = (int*)carve(64 * 4);
    int* perm      = (int*)carve(N_NODES * 4);
    unsigned short* h0   = (unsigned short*)carve((size_t)N_NODES * D * 2);
    unsigned short* h1   = (unsigned short*)carve((size_t)N_NODES * D * 2);
    unsigned short* aggb = (unsigned short*)carve((size_t)N_NODES * D * 2);
    unsigned short* Wp   = (unsigned short*)carve(65536 * 2);
    unsigned short* h2 = h0;  // reuse: h0 dead after conv1's lin
    float* out = (float*)d_out;

    const int nblk_scan = (N_NODES + 1023) / 1024;  // 49

    init_kernel<<<ZERO_BLOCKS + PACK_BLOCKS + PRE_BLOCKS, 256, 0, stream>>>(
        deg, W1_l, W1_r, W2_l, W2_r, Wp, x, W_pre, b_pre, h0);

    deg_kernel<<<(N_EDGES + 255) / 256, 256, 0, stream>>>(dst, deg);
    scan_blk_kernel<<<nblk_scan, 1024, 0, stream>>>(deg, partial, bsum);
    scan_fix_kernel<<<(N_NODES + 255) / 256, 256, 0, stream>>>(partial, bsum, deg,
                                                               row_start, cursor, deg_inv,
                                                               hist);
    perm_kernel<<<(N_NODES + 255) / 256, 256, 0, stream>>>(deg, hist, cnt2, perm);
    fill_kernel<<<(N_EDGES + 255) / 256, 256, 0, stream>>>(src, dst, cursor, csr_src);

    // conv1
    agg_kernel<<<(N_NODES + 15) / 16, 256, 0, stream>>>(h0, row_start, csr_src, deg_inv,
                                                        perm, aggb);
    lin_mfma_kernel<<<(NTILES + 3) / 4, 256, 0, stream>>>(h0, aggb, Wp, b1, h1);

    // conv2
    agg_kernel<<<(N_NODES + 15) / 16, 256, 0, stream>>>(h1, row_start, csr_src, deg_inv,
                                                        perm, aggb);
    lin_mfma_kernel<<<(NTILES + 3) / 4, 256, 0, stream>>>(h1, aggb, Wp + 32768, b2, h2);

    // pool + head
    pool_sum_kernel<<<(N_NODES + 127) / 128, 128, 0, stream>>>(h2, batch, gsum);
    mlp_kernel<<<N_GRAPHS, 128, 0, stream>>>(gsum, batch, W_p1, b_p1, W_p2, b_p2,
                                             W_out, b_out, out);
}

// Round 12
// 204.033 us; speedup vs baseline: 2.5317x; 1.0232x over previous
//
#include <hip/hip_runtime.h>
#include <hip/hip_bf16.h>

#define N_NODES 50000
#define N_EDGES 600000
#define N_GRAPHS 256
#define D 128
#define NTILES 1563  // ceil(50000/32)

typedef __bf16 bf16x8 __attribute__((ext_vector_type(8)));
typedef float f32x16 __attribute__((ext_vector_type(16)));
typedef unsigned short u16x8 __attribute__((ext_vector_type(8)));
typedef unsigned short u16x4 __attribute__((ext_vector_type(4)));

__device__ __forceinline__ float bf2f(unsigned short u) {
    unsigned v = ((unsigned)u) << 16;
    return __builtin_bit_cast(float, v);
}
__device__ __forceinline__ unsigned short f2bf(float f) {
    unsigned x = __builtin_bit_cast(unsigned, f);
    unsigned r = (x + 0x7fffu + ((x >> 16) & 1u)) >> 16;  // RNE
    return (unsigned short)r;
}

// ---------------- fused init: zero(deg+gsum) || pack_w || pre ----------------

#define ZERO_N (50048 + 32768)
#define ZERO_BLOCKS 324
#define PACK_BLOCKS 256
#define PRE_BLOCKS 3125

__global__ __launch_bounds__(256) void init_kernel(
    int* __restrict__ deg_gsum,
    const float* __restrict__ Wl1, const float* __restrict__ Wr1,
    const float* __restrict__ Wl2, const float* __restrict__ Wr2,
    unsigned short* __restrict__ Wpk,
    const float* __restrict__ x, const float* __restrict__ Wpre,
    const float* __restrict__ bpre, unsigned short* __restrict__ h0) {
    int bb = blockIdx.x;
    if (bb < ZERO_BLOCKS) {
        int i = bb * 256 + threadIdx.x;
        if (i < ZERO_N) deg_gsum[i] = 0;
    } else if (bb < ZERO_BLOCKS + PACK_BLOCKS) {
        // fragment-major pack: B-frag (kt,ct): lane l elem j = W[kt*16+(l>>5)*8+j][(l&31)*4+ct]
        int tid = (bb - ZERO_BLOCKS) * 256 + threadIdx.x;  // < 65536
        int conv = tid >> 15;
        int e = tid & 32767;
        int j = e & 7, lane = (e >> 3) & 63, ct = (e >> 9) & 3, kt = e >> 11;
        int k = kt * 16 + (lane >> 5) * 8 + j;
        int col = (lane & 31) * 4 + ct;
        const float* Wl = conv ? Wl2 : Wl1;
        const float* Wr = conv ? Wr2 : Wr1;
        float v = (k < 128) ? Wl[k * 128 + col] : Wr[(k - 128) * 128 + col];
        Wpk[tid] = f2bf(v);
    } else {
        int idx = (bb - ZERO_BLOCKS - PACK_BLOCKS) * 256 + threadIdx.x;  // node*16+slot
        if (idx >= N_NODES * 16) return;
        int node = idx >> 4, j8 = (idx & 15) * 8;
        const float* xr = x + node * 5;
        float acc[8];
#pragma unroll
        for (int c = 0; c < 8; ++c) acc[c] = bpre[j8 + c];
#pragma unroll
        for (int k = 0; k < 5; ++k) {
            float xv = xr[k];
#pragma unroll
            for (int c = 0; c < 8; ++c) acc[c] += xv * Wpre[k * D + j8 + c];
        }
        u16x8 o;
#pragma unroll
        for (int c = 0; c < 8; ++c) o[c] = f2bf(fmaxf(acc[c], 0.f));
        *(u16x8*)&h0[(size_t)node * D + j8] = o;
    }
}

// ---------------- CSR build ----------------

__global__ void deg_kernel(const int* __restrict__ dst, int* __restrict__ deg) {
    int e = blockIdx.x * 256 + threadIdx.x;
    if (e < N_EDGES) atomicAdd(&deg[dst[e]], 1);
}

// per-block exclusive scan: shfl wave-scans + LDS cross-wave combine (2 barriers)
__global__ __launch_bounds__(1024) void scan_blk_kernel(const int* __restrict__ deg,
                                                        int* __restrict__ partial,
                                                        int* __restrict__ bsum) {
    __shared__ int wsum[16];
    int tid = threadIdx.x;
    int i = blockIdx.x * 1024 + tid;
    int v = (i < N_NODES) ? deg[i] : 0;
    int lane = tid & 63, wid = tid >> 6;
    int incl = v;
#pragma unroll
    for (int m = 1; m < 64; m <<= 1) {
        int t = __shfl_up(incl, m);
        if (lane >= m) incl += t;
    }
    if (lane == 63) wsum[wid] = incl;
    __syncthreads();
    if (wid == 0) {
        int wv = (lane < 16) ? wsum[lane] : 0;
        int winc = wv;
#pragma unroll
        for (int m = 1; m < 16; m <<= 1) {
            int t = __shfl_up(winc, m);
            if (lane >= m) winc += t;
        }
        if (lane < 16) wsum[lane] = winc - wv;  // exclusive wave offsets
    }
    __syncthreads();
    int excl = incl - v + wsum[wid];
    if (i < N_NODES) partial[i] = excl;
    if (tid == 1023) bsum[blockIdx.x] = excl + v;
}

__global__ __launch_bounds__(256) void scan_fix_kernel(const int* __restrict__ partial,
                                                       const int* __restrict__ bsum,
                                                       const int* __restrict__ deg,
                                                       int* __restrict__ row_start,
                                                       int* __restrict__ cursor,
                                                       float* __restrict__ deg_inv) {
    __shared__ int boff_s;
    int bucket = (blockIdx.x * 256) >> 10;
    if (threadIdx.x < 64) {
        int l = threadIdx.x;
        int v = (l < bucket) ? bsum[l] : 0;
#pragma unroll
        for (int m = 32; m >= 1; m >>= 1) v += __shfl_xor(v, m);
        if (l == 0) boff_s = v;
    }
    __syncthreads();
    int i = blockIdx.x * 256 + threadIdx.x;
    if (i >= N_NODES) return;
    int dg = deg[i];
    int rs = partial[i] + boff_s;
    row_start[i] = rs;
    cursor[i] = rs;
    deg_inv[i] = 1.0f / fmaxf((float)dg, 1.0f);
    if (i == N_NODES - 1) row_start[N_NODES] = rs + dg;
}

__global__ void fill_kernel(const int* __restrict__ src, const int* __restrict__ dst,
                            int* __restrict__ cursor, int* __restrict__ csr_src) {
    int e = blockIdx.x * 256 + threadIdx.x;
    if (e < N_EDGES) {
        int slot = atomicAdd(&cursor[dst[e]], 1);
        csr_src[slot] = src[e];
    }
}

// ---------------- mean aggregate: one node per 16-lane group, 8-deep unroll ----------------

__global__ __launch_bounds__(256) void agg_kernel(const unsigned short* __restrict__ h,
                                                  const int* __restrict__ row_start,
                                                  const int* __restrict__ csr_src,
                                                  const float* __restrict__ deg_inv,
                                                  unsigned short* __restrict__ aggb) {
    int node = blockIdx.x * 16 + (threadIdx.x >> 4);
    int fl = threadIdx.x & 15;  // feature slot: features fl*8 .. fl*8+7
    if (node >= N_NODES) return;
    int s = row_start[node], e = row_start[node + 1];
    float a[8] = {0.f, 0.f, 0.f, 0.f, 0.f, 0.f, 0.f, 0.f};
    int i = s;
    for (; i + 7 < e; i += 8) {
        int c[8];
#pragma unroll
        for (int q = 0; q < 8; ++q) c[q] = csr_src[i + q];
        bf16x8 v[8];
#pragma unroll
        for (int q = 0; q < 8; ++q) v[q] = *(const bf16x8*)(h + (size_t)c[q] * D + fl * 8);
#pragma unroll
        for (int q = 0; q < 8; ++q)
#pragma unroll
            for (int j = 0; j < 8; ++j) a[j] += (float)v[q][j];
    }
    for (; i + 3 < e; i += 4) {
        int c[4];
#pragma unroll
        for (int q = 0; q < 4; ++q) c[q] = csr_src[i + q];
        bf16x8 v[4];
#pragma unroll
        for (int q = 0; q < 4; ++q) v[q] = *(const bf16x8*)(h + (size_t)c[q] * D + fl * 8);
#pragma unroll
        for (int q = 0; q < 4; ++q)
#pragma unroll
            for (int j = 0; j < 8; ++j) a[j] += (float)v[q][j];
    }
    for (; i < e; ++i) {
        int c0 = csr_src[i];
        bf16x8 v0 = *(const bf16x8*)(h + (size_t)c0 * D + fl * 8);
#pragma unroll
        for (int j = 0; j < 8; ++j) a[j] += (float)v0[j];
    }
    float di = deg_inv[node];
    u16x8 o;
#pragma unroll
    for (int j = 0; j < 8; ++j) o[j] = f2bf(a[j] * di);
    *(u16x8*)(aggb + (size_t)node * D + fl * 8) = o;
}

// ---------------- SAGE linear via MFMA with LDS-staged weights ----------------

__global__ __launch_bounds__(256) void lin_mfma_kernel(const unsigned short* __restrict__ hin,
                                                       const unsigned short* __restrict__ aggb,
                                                       const unsigned short* __restrict__ Wp,
                                                       const float* __restrict__ b,
                                                       unsigned short* __restrict__ hout) {
    __shared__ unsigned short Wls[32768];  // 64 KB

    int t = threadIdx.x;
    int wg = blockIdx.x * 4 + (t >> 6);
    int lane = t & 63;
    int l31 = lane & 31, hi = lane >> 5;
    int row0 = wg * 32;
    int rowg = row0 + l31;
    bool wvalid = wg < NTILES;
    int rowc = (wvalid && rowg < N_NODES) ? rowg : (N_NODES - 1);

    // prefetch A-fragments (16 x 16B per lane) while W streams to LDS
    const unsigned short* arow = aggb + (size_t)rowc * D + hi * 8;
    const unsigned short* hrow = hin + (size_t)rowc * D + hi * 8;
    bf16x8 afr[16];
#pragma unroll
    for (int kt = 0; kt < 8; ++kt) afr[kt] = *(const bf16x8*)(arow + kt * 16);
#pragma unroll
    for (int kt = 0; kt < 8; ++kt) afr[8 + kt] = *(const bf16x8*)(hrow + kt * 16);

    // stage the 64KB weight table: 4096 x 16B, 256 threads x 16 iters
#pragma unroll
    for (int q = 0; q < 16; ++q) {
        int idx = q * 256 + t;
        *(u16x8*)&Wls[idx * 8] = *(const u16x8*)&Wp[idx * 8];
    }
    __syncthreads();

    if (!wvalid) return;

    const unsigned short* wbase = Wls + lane * 8;

    f32x16 acc[4];
#pragma unroll
    for (int ct = 0; ct < 4; ++ct) acc[ct] = (f32x16)(0.0f);

#pragma unroll
    for (int kt = 0; kt < 16; ++kt) {
#pragma unroll
        for (int ct = 0; ct < 4; ++ct) {
            bf16x8 bfrag = *(const bf16x8*)(wbase + (kt * 4 + ct) * 512);
            acc[ct] = __builtin_amdgcn_mfma_f32_32x32x16_bf16(afr[kt], bfrag, acc[ct], 0, 0, 0);
        }
    }

    // epilogue: +bias, per-row L2 norm, relu, 8B store (4 consecutive cols/lane)
    float4 b4 = *(const float4*)&b[l31 * 4];
    float bb[4] = {b4.x, b4.y, b4.z, b4.w};

#pragma unroll
    for (int r = 0; r < 16; ++r) {
        float v[4];
        float ss = 0.f;
#pragma unroll
        for (int ct = 0; ct < 4; ++ct) {
            v[ct] = acc[ct][r] + bb[ct];
            ss += v[ct] * v[ct];
        }
        ss += __shfl_xor(ss, 1);
        ss += __shfl_xor(ss, 2);
        ss += __shfl_xor(ss, 4);
        ss += __shfl_xor(ss, 8);
        ss += __shfl_xor(ss, 16);
        float sc = 1.0f / fmaxf(sqrtf(ss), 1e-12f);
        int row = row0 + (r & 3) + 8 * (r >> 2) + 4 * hi;
        if (row < N_NODES) {
            u16x4 o;
#pragma unroll
            for (int ct = 0; ct < 4; ++ct) o[ct] = f2bf(fmaxf(v[ct] * sc, 0.f));
            *(u16x4*)(hout + (size_t)row * D + l31 * 4) = o;
        }
    }
}

// ---------------- global mean pool: chunk-parallel run-length atomics ----------------

__global__ __launch_bounds__(128) void pool_sum_kernel(const unsigned short* __restrict__ h,
                                                       const int* __restrict__ batch,
                                                       float* __restrict__ gsum) {
    int j = threadIdx.x;
    int i0 = blockIdx.x * 128;
    int i1 = i0 + 128;
    if (i1 > N_NODES) i1 = N_NODES;
    __shared__ int bids[128];
    if (i0 + j < N_NODES) bids[j] = batch[i0 + j];
    __syncthreads();
    float acc = 0.f;
    int cur = bids[0];
    for (int i = i0; i < i1; ++i) {
        int bid = bids[i - i0];
        if (bid != cur) {
            atomicAdd(&gsum[cur * D + j], acc);
            acc = 0.f;
            cur = bid;
        }
        acc += bf2f(h[(size_t)i * D + j]);
    }
    atomicAdd(&gsum[cur * D + j], acc);
}

// ---------------- head MLP (f32), fused mean-divide via binary search ----------------

__global__ __launch_bounds__(128) void mlp_kernel(const float* __restrict__ gsum,
                                                  const int* __restrict__ batch,
                                                  const float* __restrict__ Wp1,
                                                  const float* __restrict__ bp1,
                                                  const float* __restrict__ Wp2,
                                                  const float* __restrict__ bp2,
                                                  const float* __restrict__ Wout,
                                                  const float* __restrict__ bout,
                                                  float* __restrict__ out) {
    __shared__ float gin[128], y1[128], y2[64];
    __shared__ float cnt_s;
    int gid = blockIdx.x, j = threadIdx.x;
    if (j == 0) {
        int lo = 0, hi = N_NODES;
        while (lo < hi) { int m = (lo + hi) >> 1; if (batch[m] < gid) lo = m + 1; else hi = m; }
        int start = lo;
        lo = start; hi = N_NODES;
        while (lo < hi) { int m = (lo + hi) >> 1; if (batch[m] < gid + 1) lo = m + 1; else hi = m; }
        cnt_s = fmaxf((float)(lo - start), 1.0f);
    }
    __syncthreads();
    gin[j] = gsum[gid * 128 + j] / cnt_s;
    __syncthreads();
    float a = bp1[j];
    for (int k = 0; k < 128; ++k) a += gin[k] * Wp1[k * 128 + j];
    y1[j] = fmaxf(a, 0.f);
    __syncthreads();
    if (j < 64) {
        float a2 = bp2[j];
        for (int k = 0; k < 128; ++k) a2 += y1[k] * Wp2[k * 64 + j];
        y2[j] = fmaxf(a2, 0.f);
    }
    __syncthreads();
    if (j < 64) {
        float v = y2[j] * Wout[j];
#pragma unroll
        for (int m = 32; m >= 1; m >>= 1) v += __shfl_xor(v, m);
        if (j == 0) out[gid] = v + bout[0];
    }
}

// ---------------- launch ----------------

extern "C" void kernel_launch(void* const* d_in, const int* in_sizes, int n_in,
                              void* d_out, int out_size, void* d_ws, size_t ws_size,
                              hipStream_t stream) {
    const float* x     = (const float*)d_in[0];
    const int*   ei    = (const int*)d_in[1];
    const int*   batch = (const int*)d_in[2];
    const float* W_pre = (const float*)d_in[3];
    const float* b_pre = (const float*)d_in[4];
    const float* W1_l  = (const float*)d_in[5];
    const float* b1    = (const float*)d_in[6];
    const float* W1_r  = (const float*)d_in[7];
    const float* W2_l  = (const float*)d_in[8];
    const float* b2    = (const float*)d_in[9];
    const float* W2_r  = (const float*)d_in[10];
    const float* W_p1  = (const float*)d_in[11];
    const float* b_p1  = (const float*)d_in[12];
    const float* W_p2  = (const float*)d_in[13];
    const float* b_p2  = (const float*)d_in[14];
    const float* W_out = (const float*)d_in[15];
    const float* b_out = (const float*)d_in[16];

    const int* src = ei;
    const int* dst = ei + N_EDGES;

    size_t off = 0;
    auto carve = [&](size_t bytes) {
        void* p = (char*)d_ws + off;
        off += (bytes + 255) & ~(size_t)255;
        return p;
    };
    int* deg       = (int*)carve(50048 * 4 + 32768 * 4);
    float* gsum    = (float*)(deg + 50048);
    int* row_start = (int*)carve((N_NODES + 1) * 4);
    int* cursor    = (int*)carve(N_NODES * 4);
    int* csr_src   = (int*)carve(N_EDGES * 4);
    float* deg_inv = (float*)carve(N_NODES * 4);
    int* partial   = (int*)carve(N_NODES * 4);
    int* bsum      = (int*)carve(64 * 4);
    unsigned short* h0   = (unsigned short*)carve((size_t)N_NODES * D * 2);
    unsigned short* h1   = (unsigned short*)carve((size_t)N_NODES * D * 2);
    unsigned short* aggb = (unsigned short*)carve((size_t)N_NODES * D * 2);
    unsigned short* Wp   = (unsigned short*)carve(65536 * 2);
    unsigned short* h2 = h0;  // reuse: h0 dead after conv1's lin
    float* out = (float*)d_out;

    const int nblk_scan = (N_NODES + 1023) / 1024;  // 49

    init_kernel<<<ZERO_BLOCKS + PACK_BLOCKS + PRE_BLOCKS, 256, 0, stream>>>(
        deg, W1_l, W1_r, W2_l, W2_r, Wp, x, W_pre, b_pre, h0);

    deg_kernel<<<(N_EDGES + 255) / 256, 256, 0, stream>>>(dst, deg);
    scan_blk_kernel<<<nblk_scan, 1024, 0, stream>>>(deg, partial, bsum);
    scan_fix_kernel<<<(N_NODES + 255) / 256, 256, 0, stream>>>(partial, bsum, deg,
                                                               row_start, cursor, deg_inv);
    fill_kernel<<<(N_EDGES + 255) / 256, 256, 0, stream>>>(src, dst, cursor, csr_src);

    // conv1
    agg_kernel<<<(N_NODES + 15) / 16, 256, 0, stream>>>(h0, row_start, csr_src, deg_inv, aggb);
    lin_mfma_kernel<<<(NTILES + 3) / 4, 256, 0, stream>>>(h0, aggb, Wp, b1, h1);

    // conv2
    agg_kernel<<<(N_NODES + 15) / 16, 256, 0, stream>>>(h1, row_start, csr_src, deg_inv, aggb);
    lin_mfma_kernel<<<(NTILES + 3) / 4, 256, 0, stream>>>(h1, aggb, Wp + 32768, b2, h2);

    // pool + head
    pool_sum_kernel<<<(N_NODES + 127) / 128, 128, 0, stream>>>(h2, batch, gsum);
    mlp_kernel<<<N_GRAPHS, 128, 0, stream>>>(gsum, batch, W_p1, b_p1, W_p2, b_p2,
                                             W_out, b_out, out);
}

// Round 13
// 203.187 us; speedup vs baseline: 2.5422x; 1.0042x over previous
//
#include <hip/hip_runtime.h>
#include <hip/hip_bf16.h>

#define N_NODES 50000
#define N_EDGES 600000
#define N_GRAPHS 256
#define D 128
#define NTILES 1563  // ceil(50000/32)

typedef __bf16 bf16x8 __attribute__((ext_vector_type(8)));
typedef float f32x16 __attribute__((ext_vector_type(16)));
typedef unsigned short u16x8 __attribute__((ext_vector_type(8)));
typedef unsigned short u16x4 __attribute__((ext_vector_type(4)));

__device__ __forceinline__ float bf2f(unsigned short u) {
    unsigned v = ((unsigned)u) << 16;
    return __builtin_bit_cast(float, v);
}
__device__ __forceinline__ unsigned short f2bf(float f) {
    unsigned x = __builtin_bit_cast(unsigned, f);
    unsigned r = (x + 0x7fffu + ((x >> 16) & 1u)) >> 16;  // RNE
    return (unsigned short)r;
}

// ---------------- fused init: zero(deg+gsum) || pack_w || pre ----------------

#define ZERO_N (50048 + 32768)
#define ZERO_BLOCKS 324
#define PACK_BLOCKS 256
#define PRE_BLOCKS 3125

__global__ __launch_bounds__(256) void init_kernel(
    int* __restrict__ deg_gsum,
    const float* __restrict__ Wl1, const float* __restrict__ Wr1,
    const float* __restrict__ Wl2, const float* __restrict__ Wr2,
    unsigned short* __restrict__ Wpk,
    const float* __restrict__ x, const float* __restrict__ Wpre,
    const float* __restrict__ bpre, unsigned short* __restrict__ h0) {
    int bb = blockIdx.x;
    if (bb < ZERO_BLOCKS) {
        int i = bb * 256 + threadIdx.x;
        if (i < ZERO_N) deg_gsum[i] = 0;
    } else if (bb < ZERO_BLOCKS + PACK_BLOCKS) {
        // fragment-major pack: B-frag (kt,ct): lane l elem j = W[kt*16+(l>>5)*8+j][(l&31)*4+ct]
        int tid = (bb - ZERO_BLOCKS) * 256 + threadIdx.x;  // < 65536
        int conv = tid >> 15;
        int e = tid & 32767;
        int j = e & 7, lane = (e >> 3) & 63, ct = (e >> 9) & 3, kt = e >> 11;
        int k = kt * 16 + (lane >> 5) * 8 + j;
        int col = (lane & 31) * 4 + ct;
        const float* Wl = conv ? Wl2 : Wl1;
        const float* Wr = conv ? Wr2 : Wr1;
        float v = (k < 128) ? Wl[k * 128 + col] : Wr[(k - 128) * 128 + col];
        Wpk[tid] = f2bf(v);
    } else {
        int idx = (bb - ZERO_BLOCKS - PACK_BLOCKS) * 256 + threadIdx.x;  // node*16+slot
        if (idx >= N_NODES * 16) return;
        int node = idx >> 4, j8 = (idx & 15) * 8;
        const float* xr = x + node * 5;
        float acc[8];
#pragma unroll
        for (int c = 0; c < 8; ++c) acc[c] = bpre[j8 + c];
#pragma unroll
        for (int k = 0; k < 5; ++k) {
            float xv = xr[k];
#pragma unroll
            for (int c = 0; c < 8; ++c) acc[c] += xv * Wpre[k * D + j8 + c];
        }
        u16x8 o;
#pragma unroll
        for (int c = 0; c < 8; ++c) o[c] = f2bf(fmaxf(acc[c], 0.f));
        *(u16x8*)&h0[(size_t)node * D + j8] = o;
    }
}

// ---------------- CSR build (2 edges per thread) ----------------

__global__ void deg_kernel(const int* __restrict__ dst, int* __restrict__ deg) {
    int i = blockIdx.x * 256 + threadIdx.x;
    if (i * 2 < N_EDGES) {
        int2 d = *(const int2*)(dst + i * 2);
        atomicAdd(&deg[d.x], 1);
        atomicAdd(&deg[d.y], 1);
    }
}

// per-block exclusive scan: shfl wave-scans + LDS cross-wave combine (2 barriers)
__global__ __launch_bounds__(1024) void scan_blk_kernel(const int* __restrict__ deg,
                                                        int* __restrict__ partial,
                                                        int* __restrict__ bsum) {
    __shared__ int wsum[16];
    int tid = threadIdx.x;
    int i = blockIdx.x * 1024 + tid;
    int v = (i < N_NODES) ? deg[i] : 0;
    int lane = tid & 63, wid = tid >> 6;
    int incl = v;
#pragma unroll
    for (int m = 1; m < 64; m <<= 1) {
        int t = __shfl_up(incl, m);
        if (lane >= m) incl += t;
    }
    if (lane == 63) wsum[wid] = incl;
    __syncthreads();
    if (wid == 0) {
        int wv = (lane < 16) ? wsum[lane] : 0;
        int winc = wv;
#pragma unroll
        for (int m = 1; m < 16; m <<= 1) {
            int t = __shfl_up(winc, m);
            if (lane >= m) winc += t;
        }
        if (lane < 16) wsum[lane] = winc - wv;  // exclusive wave offsets
    }
    __syncthreads();
    int excl = incl - v + wsum[wid];
    if (i < N_NODES) partial[i] = excl;
    if (tid == 1023) bsum[blockIdx.x] = excl + v;
}

__global__ __launch_bounds__(256) void scan_fix_kernel(const int* __restrict__ partial,
                                                       const int* __restrict__ bsum,
                                                       const int* __restrict__ deg,
                                                       int* __restrict__ row_start,
                                                       int* __restrict__ cursor,
                                                       float* __restrict__ deg_inv) {
    __shared__ int boff_s;
    int bucket = (blockIdx.x * 256) >> 10;
    if (threadIdx.x < 64) {
        int l = threadIdx.x;
        int v = (l < bucket) ? bsum[l] : 0;
#pragma unroll
        for (int m = 32; m >= 1; m >>= 1) v += __shfl_xor(v, m);
        if (l == 0) boff_s = v;
    }
    __syncthreads();
    int i = blockIdx.x * 256 + threadIdx.x;
    if (i >= N_NODES) return;
    int dg = deg[i];
    int rs = partial[i] + boff_s;
    row_start[i] = rs;
    cursor[i] = rs;
    deg_inv[i] = 1.0f / fmaxf((float)dg, 1.0f);
    if (i == N_NODES - 1) row_start[N_NODES] = rs + dg;
}

__global__ void fill_kernel(const int* __restrict__ src, const int* __restrict__ dst,
                            int* __restrict__ cursor, int* __restrict__ csr_src) {
    int i = blockIdx.x * 256 + threadIdx.x;
    if (i * 2 < N_EDGES) {
        int2 s = *(const int2*)(src + i * 2);
        int2 d = *(const int2*)(dst + i * 2);
        int slot0 = atomicAdd(&cursor[d.x], 1);
        csr_src[slot0] = s.x;
        int slot1 = atomicAdd(&cursor[d.y], 1);
        csr_src[slot1] = s.y;
    }
}

// ---------------- mean aggregate: one node per 16-lane group, 8-deep unroll ----------------

__global__ __launch_bounds__(256) void agg_kernel(const unsigned short* __restrict__ h,
                                                  const int* __restrict__ row_start,
                                                  const int* __restrict__ csr_src,
                                                  const float* __restrict__ deg_inv,
                                                  unsigned short* __restrict__ aggb) {
    int node = blockIdx.x * 16 + (threadIdx.x >> 4);
    int fl = threadIdx.x & 15;  // feature slot: features fl*8 .. fl*8+7
    if (node >= N_NODES) return;
    int s = row_start[node], e = row_start[node + 1];
    float a[8] = {0.f, 0.f, 0.f, 0.f, 0.f, 0.f, 0.f, 0.f};
    int i = s;
    for (; i + 7 < e; i += 8) {
        int c[8];
#pragma unroll
        for (int q = 0; q < 8; ++q) c[q] = csr_src[i + q];
        bf16x8 v[8];
#pragma unroll
        for (int q = 0; q < 8; ++q) v[q] = *(const bf16x8*)(h + (size_t)c[q] * D + fl * 8);
#pragma unroll
        for (int q = 0; q < 8; ++q)
#pragma unroll
            for (int j = 0; j < 8; ++j) a[j] += (float)v[q][j];
    }
    for (; i + 3 < e; i += 4) {
        int c[4];
#pragma unroll
        for (int q = 0; q < 4; ++q) c[q] = csr_src[i + q];
        bf16x8 v[4];
#pragma unroll
        for (int q = 0; q < 4; ++q) v[q] = *(const bf16x8*)(h + (size_t)c[q] * D + fl * 8);
#pragma unroll
        for (int q = 0; q < 4; ++q)
#pragma unroll
            for (int j = 0; j < 8; ++j) a[j] += (float)v[q][j];
    }
    for (; i < e; ++i) {
        int c0 = csr_src[i];
        bf16x8 v0 = *(const bf16x8*)(h + (size_t)c0 * D + fl * 8);
#pragma unroll
        for (int j = 0; j < 8; ++j) a[j] += (float)v0[j];
    }
    float di = deg_inv[node];
    u16x8 o;
#pragma unroll
    for (int j = 0; j < 8; ++j) o[j] = f2bf(a[j] * di);
    *(u16x8*)(aggb + (size_t)node * D + fl * 8) = o;
}

// ---------------- SAGE linear via MFMA with LDS-staged weights ----------------

__global__ __launch_bounds__(256) void lin_mfma_kernel(const unsigned short* __restrict__ hin,
                                                       const unsigned short* __restrict__ aggb,
                                                       const unsigned short* __restrict__ Wp,
                                                       const float* __restrict__ b,
                                                       unsigned short* __restrict__ hout) {
    __shared__ unsigned short Wls[32768];  // 64 KB

    int t = threadIdx.x;
    int wg = blockIdx.x * 4 + (t >> 6);
    int lane = t & 63;
    int l31 = lane & 31, hi = lane >> 5;
    int row0 = wg * 32;
    int rowg = row0 + l31;
    bool wvalid = wg < NTILES;
    int rowc = (wvalid && rowg < N_NODES) ? rowg : (N_NODES - 1);

    // prefetch A-fragments (16 x 16B per lane) while W streams to LDS
    const unsigned short* arow = aggb + (size_t)rowc * D + hi * 8;
    const unsigned short* hrow = hin + (size_t)rowc * D + hi * 8;
    bf16x8 afr[16];
#pragma unroll
    for (int kt = 0; kt < 8; ++kt) afr[kt] = *(const bf16x8*)(arow + kt * 16);
#pragma unroll
    for (int kt = 0; kt < 8; ++kt) afr[8 + kt] = *(const bf16x8*)(hrow + kt * 16);

    // stage the 64KB weight table: 4096 x 16B, 256 threads x 16 iters
#pragma unroll
    for (int q = 0; q < 16; ++q) {
        int idx = q * 256 + t;
        *(u16x8*)&Wls[idx * 8] = *(const u16x8*)&Wp[idx * 8];
    }
    __syncthreads();

    if (!wvalid) return;

    const unsigned short* wbase = Wls + lane * 8;

    f32x16 acc[4];
#pragma unroll
    for (int ct = 0; ct < 4; ++ct) acc[ct] = (f32x16)(0.0f);

#pragma unroll
    for (int kt = 0; kt < 16; ++kt) {
#pragma unroll
        for (int ct = 0; ct < 4; ++ct) {
            bf16x8 bfrag = *(const bf16x8*)(wbase + (kt * 4 + ct) * 512);
            acc[ct] = __builtin_amdgcn_mfma_f32_32x32x16_bf16(afr[kt], bfrag, acc[ct], 0, 0, 0);
        }
    }

    // epilogue: +bias, per-row L2 norm, relu, 8B store (4 consecutive cols/lane)
    float4 b4 = *(const float4*)&b[l31 * 4];
    float bb[4] = {b4.x, b4.y, b4.z, b4.w};

#pragma unroll
    for (int r = 0; r < 16; ++r) {
        float v[4];
        float ss = 0.f;
#pragma unroll
        for (int ct = 0; ct < 4; ++ct) {
            v[ct] = acc[ct][r] + bb[ct];
            ss += v[ct] * v[ct];
        }
        ss += __shfl_xor(ss, 1);
        ss += __shfl_xor(ss, 2);
        ss += __shfl_xor(ss, 4);
        ss += __shfl_xor(ss, 8);
        ss += __shfl_xor(ss, 16);
        float sc = 1.0f / fmaxf(sqrtf(ss), 1e-12f);
        int row = row0 + (r & 3) + 8 * (r >> 2) + 4 * hi;
        if (row < N_NODES) {
            u16x4 o;
#pragma unroll
            for (int ct = 0; ct < 4; ++ct) o[ct] = f2bf(fmaxf(v[ct] * sc, 0.f));
            *(u16x4*)(hout + (size_t)row * D + l31 * 4) = o;
        }
    }
}

// ---------------- global mean pool: chunk-parallel run-length atomics ----------------

__global__ __launch_bounds__(128) void pool_sum_kernel(const unsigned short* __restrict__ h,
                                                       const int* __restrict__ batch,
                                                       float* __restrict__ gsum) {
    int j = threadIdx.x;
    int i0 = blockIdx.x * 128;
    int i1 = i0 + 128;
    if (i1 > N_NODES) i1 = N_NODES;
    __shared__ int bids[128];
    if (i0 + j < N_NODES) bids[j] = batch[i0 + j];
    __syncthreads();
    float acc = 0.f;
    int cur = bids[0];
    for (int i = i0; i < i1; ++i) {
        int bid = bids[i - i0];
        if (bid != cur) {
            atomicAdd(&gsum[cur * D + j], acc);
            acc = 0.f;
            cur = bid;
        }
        acc += bf2f(h[(size_t)i * D + j]);
    }
    atomicAdd(&gsum[cur * D + j], acc);
}

// ---------------- head MLP (f32), fused mean-divide via binary search ----------------

__global__ __launch_bounds__(128) void mlp_kernel(const float* __restrict__ gsum,
                                                  const int* __restrict__ batch,
                                                  const float* __restrict__ Wp1,
                                                  const float* __restrict__ bp1,
                                                  const float* __restrict__ Wp2,
                                                  const float* __restrict__ bp2,
                                                  const float* __restrict__ Wout,
                                                  const float* __restrict__ bout,
                                                  float* __restrict__ out) {
    __shared__ float gin[128], y1[128], y2[64];
    __shared__ float cnt_s;
    int gid = blockIdx.x, j = threadIdx.x;
    if (j == 0) {
        int lo = 0, hi = N_NODES;
        while (lo < hi) { int m = (lo + hi) >> 1; if (batch[m] < gid) lo = m + 1; else hi = m; }
        int start = lo;
        lo = start; hi = N_NODES;
        while (lo < hi) { int m = (lo + hi) >> 1; if (batch[m] < gid + 1) lo = m + 1; else hi = m; }
        cnt_s = fmaxf((float)(lo - start), 1.0f);
    }
    __syncthreads();
    gin[j] = gsum[gid * 128 + j] / cnt_s;
    __syncthreads();
    float a = bp1[j];
    for (int k = 0; k < 128; ++k) a += gin[k] * Wp1[k * 128 + j];
    y1[j] = fmaxf(a, 0.f);
    __syncthreads();
    if (j < 64) {
        float a2 = bp2[j];
        for (int k = 0; k < 128; ++k) a2 += y1[k] * Wp2[k * 64 + j];
        y2[j] = fmaxf(a2, 0.f);
    }
    __syncthreads();
    if (j < 64) {
        float v = y2[j] * Wout[j];
#pragma unroll
        for (int m = 32; m >= 1; m >>= 1) v += __shfl_xor(v, m);
        if (j == 0) out[gid] = v + bout[0];
    }
}

// ---------------- launch ----------------

extern "C" void kernel_launch(void* const* d_in, const int* in_sizes, int n_in,
                              void* d_out, int out_size, void* d_ws, size_t ws_size,
                              hipStream_t stream) {
    const float* x     = (const float*)d_in[0];
    const int*   ei    = (const int*)d_in[1];
    const int*   batch = (const int*)d_in[2];
    const float* W_pre = (const float*)d_in[3];
    const float* b_pre = (const float*)d_in[4];
    const float* W1_l  = (const float*)d_in[5];
    const float* b1    = (const float*)d_in[6];
    const float* W1_r  = (const float*)d_in[7];
    const float* W2_l  = (const float*)d_in[8];
    const float* b2    = (const float*)d_in[9];
    const float* W2_r  = (const float*)d_in[10];
    const float* W_p1  = (const float*)d_in[11];
    const float* b_p1  = (const float*)d_in[12];
    const float* W_p2  = (const float*)d_in[13];
    const float* b_p2  = (const float*)d_in[14];
    const float* W_out = (const float*)d_in[15];
    const float* b_out = (const float*)d_in[16];

    const int* src = ei;
    const int* dst = ei + N_EDGES;

    size_t off = 0;
    auto carve = [&](size_t bytes) {
        void* p = (char*)d_ws + off;
        off += (bytes + 255) & ~(size_t)255;
        return p;
    };
    int* deg       = (int*)carve(50048 * 4 + 32768 * 4);
    float* gsum    = (float*)(deg + 50048);
    int* row_start = (int*)carve((N_NODES + 1) * 4);
    int* cursor    = (int*)carve(N_NODES * 4);
    int* csr_src   = (int*)carve(N_EDGES * 4);
    float* deg_inv = (float*)carve(N_NODES * 4);
    int* partial   = (int*)carve(N_NODES * 4);
    int* bsum      = (int*)carve(64 * 4);
    unsigned short* h0   = (unsigned short*)carve((size_t)N_NODES * D * 2);
    unsigned short* h1   = (unsigned short*)carve((size_t)N_NODES * D * 2);
    unsigned short* aggb = (unsigned short*)carve((size_t)N_NODES * D * 2);
    unsigned short* Wp   = (unsigned short*)carve(65536 * 2);
    unsigned short* h2 = h0;  // reuse: h0 dead after conv1's lin
    float* out = (float*)d_out;

    const int nblk_scan = (N_NODES + 1023) / 1024;  // 49
    const int nblk_edge2 = (N_EDGES / 2 + 255) / 256;  // 1172

    init_kernel<<<ZERO_BLOCKS + PACK_BLOCKS + PRE_BLOCKS, 256, 0, stream>>>(
        deg, W1_l, W1_r, W2_l, W2_r, Wp, x, W_pre, b_pre, h0);

    deg_kernel<<<nblk_edge2, 256, 0, stream>>>(dst, deg);
    scan_blk_kernel<<<nblk_scan, 1024, 0, stream>>>(deg, partial, bsum);
    scan_fix_kernel<<<(N_NODES + 255) / 256, 256, 0, stream>>>(partial, bsum, deg,
                                                               row_start, cursor, deg_inv);
    fill_kernel<<<nblk_edge2, 256, 0, stream>>>(src, dst, cursor, csr_src);

    // conv1
    agg_kernel<<<(N_NODES + 15) / 16, 256, 0, stream>>>(h0, row_start, csr_src, deg_inv, aggb);
    lin_mfma_kernel<<<(NTILES + 3) / 4, 256, 0, stream>>>(h0, aggb, Wp, b1, h1);

    // conv2
    agg_kernel<<<(N_NODES + 15) / 16, 256, 0, stream>>>(h1, row_start, csr_src, deg_inv, aggb);
    lin_mfma_kernel<<<(NTILES + 3) / 4, 256, 0, stream>>>(h1, aggb, Wp + 32768, b2, h2);

    // pool + head
    pool_sum_kernel<<<(N_NODES + 127) / 128, 128, 0, stream>>>(h2, batch, gsum);
    mlp_kernel<<<N_GRAPHS, 128, 0, stream>>>(gsum, batch, W_p1, b_p1, W_p2, b_p2,
                                             W_out, b_out, out);
}